// Round 7
// baseline (2185.058 us; speedup 1.0000x reference)
//
#include <hip/hip_runtime.h>
#include <stdint.h>

typedef short short8 __attribute__((ext_vector_type(8)));
typedef float f32x4 __attribute__((ext_vector_type(4)));
typedef float f32x16 __attribute__((ext_vector_type(16)));

#define N_NODES 500
#define HGC 16
#define DH 512
#define T_STEPS 64
#define NB 32
#define F_IN 8
#define DSTEPS 16
#define E_EDGES 16000
#define E_TOT 16500
#define NH 8000          // N*HG
#define G3 1536          // 3*D
#define BT 2048          // B*T
#define DKC 10           // decoder K-split
#define DBLK 120         // decoder persistent blocks (12 ntiles x 10 kc)

__device__ __forceinline__ unsigned short f2bf(float x) {
  unsigned int u = __float_as_uint(x);
  u = (u + 0x7fffu + ((u >> 16) & 1u)) >> 16;
  return (unsigned short)u;
}

__device__ __forceinline__ void gl_lds16(const void* g, void* l) {
  __builtin_amdgcn_global_load_lds((const __attribute__((address_space(1))) void*)g,
                                   (__attribute__((address_space(3))) void*)l, 16, 0, 0);
}

__device__ __forceinline__ float sigm(float x) { return 1.f / (1.f + __expf(-x)); }

// ---------------- graph prep ----------------
__global__ void k_deg_init(int* deg) {
  int t = blockIdx.x * blockDim.x + threadIdx.x;
  if (t < N_NODES) deg[t] = 1;  // self loop
}

__global__ void k_deg_count(const int* __restrict__ ei, int* deg) {
  int t = blockIdx.x * blockDim.x + threadIdx.x;
  if (t < E_EDGES) atomicAdd(&deg[ei[E_EDGES + t]], 1);
}

__global__ void k_scan(const int* __restrict__ deg, float* dinv, int* rowptr, int* cursor) {
  __shared__ int s[512];
  int t = threadIdx.x;
  int v = (t < N_NODES) ? deg[t] : 0;
  s[t] = v;
  __syncthreads();
  for (int off = 1; off < 512; off <<= 1) {
    int add = (t >= off) ? s[t - off] : 0;
    __syncthreads();
    s[t] += add;
    __syncthreads();
  }
  if (t < N_NODES) {
    int excl = s[t] - v;
    rowptr[t] = excl;
    cursor[t] = excl;
    dinv[t] = rsqrtf((float)v);
  }
  if (t == 0) rowptr[N_NODES] = s[511];
}

__global__ void k_scatter(const int* __restrict__ ei, const float* __restrict__ dinv,
                          int* cursor, int* col, float* nrm) {
  int t = blockIdx.x * blockDim.x + threadIdx.x;
  if (t >= E_TOT) return;
  int s_, d_;
  if (t < E_EDGES) { s_ = ei[t]; d_ = ei[E_EDGES + t]; }
  else { s_ = d_ = t - E_EDGES; }
  int pos = atomicAdd(&cursor[d_], 1);
  col[pos] = s_;
  nrm[pos] = dinv[s_] * dinv[d_];
}

// ---------------- f32 -> bf16 bulk convert ----------------
__global__ void k_f2bf4(const float* __restrict__ src, unsigned short* __restrict__ dst, int n4) {
  int i = blockIdx.x * blockDim.x + threadIdx.x;
  if (i >= n4) return;
  float4 v = ((const float4*)src)[i];
  ushort4 o;
  o.x = f2bf(v.x); o.y = f2bf(v.y); o.z = f2bf(v.z); o.w = f2bf(v.w);
  ((ushort4*)dst)[i] = o;
}

// ---------------- x (2048,500,8) f32 -> xT2 (16384, 512) bf16 (zero-padded cols) ----------------
__global__ __launch_bounds__(256) void k_transpose(const float* __restrict__ x,
                                                   unsigned short* __restrict__ xT2) {
  __shared__ float xs[N_NODES * 9];
  int g = blockIdx.x, t = threadIdx.x;
  const float4* xg = (const float4*)(x + (size_t)g * (N_NODES * F_IN));
  for (int i = t; i < N_NODES * 2; i += 256) {
    float4 v = xg[i];
    int n = i >> 1, fh = (i & 1) * 4;
    float* d = &xs[n * 9 + fh];
    d[0] = v.x; d[1] = v.y; d[2] = v.z; d[3] = v.w;
  }
  __syncthreads();
  int f = t >> 5, u = t & 31;
  short8 lo, hi;
#pragma unroll
  for (int j = 0; j < 8; ++j) {
    int n0 = u * 16 + j, n1 = n0 + 8;
    lo[j] = (short)((n0 < N_NODES) ? f2bf(xs[n0 * 9 + f]) : 0);
    hi[j] = (short)((n1 < N_NODES) ? f2bf(xs[n1 * 9 + f]) : 0);
  }
  unsigned short* dst = xT2 + (size_t)(g * 8 + f) * 512 + u * 16;
  *(short8*)dst = lo;
  *(short8*)(dst + 8) = hi;
}

// ---------------- densify Ahat rows (by dst) -> (512, 512) bf16 ----------------
__global__ __launch_bounds__(256) void k_densify(const int* __restrict__ rowptr,
                                                 const int* __restrict__ col,
                                                 const float* __restrict__ nrm,
                                                 unsigned short* __restrict__ AhatD) {
  __shared__ float row[512];
  int n = blockIdx.x, t = threadIdx.x;
  row[t] = 0.f; row[t + 256] = 0.f;
  __syncthreads();
  if (n < N_NODES) {
    int e1 = rowptr[n + 1];
    for (int e = rowptr[n] + t; e < e1; e += 256) atomicAdd(&row[col[e]], nrm[e]);
  }
  __syncthreads();
  AhatD[n * 512 + t] = f2bf(row[t]);
  AhatD[n * 512 + t + 256] = f2bf(row[t + 256]);
}

// ---------------- agg GEMM: C(16384 gf, 512 n) = xT2 . AhatD^T ; fused W(8->16)+relu -> emb ----------------
__global__ __launch_bounds__(256) void k_gemm_agg(const unsigned short* __restrict__ A,
                                                  const unsigned short* __restrict__ B,
                                                  const float* __restrict__ W,
                                                  const float* __restrict__ bias,
                                                  unsigned short* __restrict__ emb) {
  __shared__ float smem[64 * 129];
  __shared__ float Wsm[F_IN * HGC];
  __shared__ float bsm[HGC];
  unsigned short* As = (unsigned short*)smem;
  unsigned short* Bs = As + 4096;
  int t = threadIdx.x;
  if (t < F_IN * HGC) Wsm[t] = W[t];
  if (t < HGC) bsm[t] = bias[t];
  int m0 = blockIdx.x * 128, n0 = blockIdx.y * 128;
  int wave = t >> 6, lane = t & 63;
  int mh = (wave >> 1) * 64, nh = (wave & 1) * 64;
  int lrow = t >> 2, lslot = t & 3;
  f32x4 acc[4][4];
#pragma unroll
  for (int a = 0; a < 4; ++a)
#pragma unroll
    for (int b = 0; b < 4; ++b) acc[a][b] = (f32x4){0.f, 0.f, 0.f, 0.f};
  const unsigned short* ga0 = A + (size_t)(m0 + lrow) * 512 + lslot * 8;
  const unsigned short* ga1 = A + (size_t)(m0 + 64 + lrow) * 512 + lslot * 8;
  const unsigned short* gb0 = B + (size_t)(n0 + lrow) * 512 + lslot * 8;
  const unsigned short* gb1 = B + (size_t)(n0 + 64 + lrow) * 512 + lslot * 8;
  int rl = lane & 15, ks = lane >> 4;
  for (int kt = 0; kt < 16; ++kt) {
    int k0 = kt * 32;
    gl_lds16(ga0 + k0, &As[t * 8]);
    gl_lds16(ga1 + k0, &As[2048 + t * 8]);
    gl_lds16(gb0 + k0, &Bs[t * 8]);
    gl_lds16(gb1 + k0, &Bs[2048 + t * 8]);
    __syncthreads();
    short8 af[4], bfr[4];
#pragma unroll
    for (int mf = 0; mf < 4; ++mf) af[mf] = *(const short8*)&As[(mh + mf * 16 + rl) * 32 + ks * 8];
#pragma unroll
    for (int nf = 0; nf < 4; ++nf) bfr[nf] = *(const short8*)&Bs[(nh + nf * 16 + rl) * 32 + ks * 8];
#pragma unroll
    for (int mf = 0; mf < 4; ++mf)
#pragma unroll
      for (int nf = 0; nf < 4; ++nf)
        acc[mf][nf] = __builtin_amdgcn_mfma_f32_16x16x32_bf16(af[mf], bfr[nf], acc[mf][nf], 0, 0, 0);
    __syncthreads();
  }
  int rg = lane >> 4;
  for (int p = 0; p < 2; ++p) {
    if ((wave >> 1) == p) {
#pragma unroll
      for (int mf = 0; mf < 4; ++mf)
#pragma unroll
        for (int nf = 0; nf < 4; ++nf)
#pragma unroll
          for (int q = 0; q < 4; ++q)
            smem[(mf * 16 + rg * 4 + q) * 129 + nh + nf * 16 + rl] = acc[mf][nf][q];
    }
    __syncthreads();
    int gl = t >> 5, sub = t & 31;
    int g = blockIdx.x * 16 + p * 8 + gl;
#pragma unroll
    for (int j = 0; j < 4; ++j) {
      int nl = sub + 32 * j, ng = n0 + nl;
      if (ng < N_NODES) {
        float v[8];
#pragma unroll
        for (int f = 0; f < 8; ++f) v[f] = smem[(gl * 8 + f) * 129 + nl];
        short8 o0, o1;
#pragma unroll
        for (int c = 0; c < 8; ++c) {
          float s0 = bsm[c], s1 = bsm[c + 8];
#pragma unroll
          for (int f = 0; f < 8; ++f) {
            s0 += v[f] * Wsm[f * 16 + c];
            s1 += v[f] * Wsm[f * 16 + c + 8];
          }
          o0[c] = (short)f2bf(fmaxf(s0, 0.f));
          o1[c] = (short)f2bf(fmaxf(s1, 0.f));
        }
        unsigned short* dst = emb + (size_t)g * NH + ng * 16;
        *(short8*)dst = o0;
        *(short8*)(dst + 8) = o1;
      }
    }
    __syncthreads();
  }
}

// ---------------- big encoder GEMM: gi = emb(2048x8000) . Wih(1536x8000)^T ----------------
// 128(M)x64(N) tiles, grid (16,24). Writes into scan layout giP2[s][blk][gate][b][cc].
__global__ __launch_bounds__(256) void k_gemm_enc(
    const unsigned short* __restrict__ A, const unsigned short* __restrict__ Bm,
    float* __restrict__ giP2) {
  __shared__ unsigned short As[128 * 32];
  __shared__ unsigned short Bs[64 * 32];
  int t = threadIdx.x;
  int m0 = blockIdx.x * 128, n0 = blockIdx.y * 64;
  int wave = t >> 6, lane = t & 63;
  int mh = (wave >> 1) * 64, nh = (wave & 1) * 32;
  int lrow = t >> 2, lslot = t & 3;
  f32x4 acc[4][2];
#pragma unroll
  for (int a = 0; a < 4; ++a)
#pragma unroll
    for (int b = 0; b < 2; ++b) acc[a][b] = (f32x4){0.f, 0.f, 0.f, 0.f};
  const unsigned short* ga0 = A + (size_t)(m0 + lrow) * NH + lslot * 8;
  const unsigned short* ga1 = A + (size_t)(m0 + 64 + lrow) * NH + lslot * 8;
  const unsigned short* gb0 = Bm + (size_t)(n0 + lrow) * NH + lslot * 8;
  int rl = lane & 15, ks = lane >> 4;
  for (int kt = 0; kt < 250; ++kt) {
    int k0 = kt * 32;
    gl_lds16(ga0 + k0, &As[t * 8]);
    gl_lds16(ga1 + k0, &As[2048 + t * 8]);
    gl_lds16(gb0 + k0, &Bs[t * 8]);
    __syncthreads();
    short8 af[4], bfr[2];
#pragma unroll
    for (int mf = 0; mf < 4; ++mf) af[mf] = *(const short8*)&As[(mh + mf * 16 + rl) * 32 + ks * 8];
#pragma unroll
    for (int nf = 0; nf < 2; ++nf) bfr[nf] = *(const short8*)&Bs[(nh + nf * 16 + rl) * 32 + ks * 8];
#pragma unroll
    for (int mf = 0; mf < 4; ++mf)
#pragma unroll
      for (int nf = 0; nf < 2; ++nf)
        acc[mf][nf] = __builtin_amdgcn_mfma_f32_16x16x32_bf16(af[mf], bfr[nf], acc[mf][nf], 0, 0, 0);
    __syncthreads();
  }
  int rg = lane >> 4;
  int gate = n0 >> 9;
#pragma unroll
  for (int mf = 0; mf < 4; ++mf)
#pragma unroll
    for (int nf = 0; nf < 2; ++nf) {
      int n = n0 + nh + nf * 16 + rl;
      int d = n & 511, blk = d >> 5, cc = d & 31;
#pragma unroll
      for (int q = 0; q < 4; ++q) {
        int m = m0 + mh + mf * 16 + rg * 4 + q;
        int s = m & 63, bb = m >> 6;
        giP2[(size_t)(s * 16 + blk) * 3072 + gate * 1024 + bb * 32 + cc] = acc[mf][nf][q];
      }
    }
}

// ---------------- shared GRU helpers ----------------
__device__ __forceinline__ void stage_hb(const unsigned short* __restrict__ src,
                                         unsigned short* hb, int t) {
  int bw = t >> 3, i8 = t & 7;
  short8 v[8];
#pragma unroll
  for (int i = 0; i < 8; ++i)
    v[i] = *(const short8*)((const char*)src + bw * 1024 + i8 * 128 + i * 16);
#pragma unroll
  for (int i = 0; i < 8; ++i) {
    int kb = i8 * 128 + i * 16;
    *(short8*)((char*)hb + bw * 1024 + (kb ^ ((bw & 15) << 4))) = v[i];
  }
}

__device__ __forceinline__ void gru_core_g(const unsigned short* __restrict__ whhB,
                                           const unsigned short* hb, float* gh,
                                           int t, int c0) {
  int lane = t & 63, g = t >> 6;
  int b31 = lane & 31, kg = lane >> 5;
  if (g < 3) {
    f32x16 acc;
#pragma unroll
    for (int q = 0; q < 16; ++q) acc[q] = 0.f;
    const unsigned short* brow = whhB + (size_t)(g * 512 + c0 + b31) * 512 + kg * 8;
    int asw = (b31 & 15) << 4;
#pragma unroll 4
    for (int kk = 0; kk < 32; ++kk) {
      int kb = (kk * 32 + kg * 16) ^ asw;
      short8 a = *(const short8*)((const char*)hb + b31 * 1024 + kb);
      short8 b = *(const short8*)(brow + kk * 16);
      acc = __builtin_amdgcn_mfma_f32_32x32x16_bf16(a, b, acc, 0, 0, 0);
    }
#pragma unroll
    for (int q = 0; q < 16; ++q) {
      int br = (q & 3) + 8 * (q >> 2) + 4 * kg;
      gh[g * 1024 + br * 32 + b31] = acc[q];
    }
  }
}

__device__ __forceinline__ void gru_gates(const float* gi, const float* gh,
                                          const float* __restrict__ bih,
                                          const float* __restrict__ bhh,
                                          float* __restrict__ hF,
                                          unsigned short* __restrict__ hb_out,
                                          int t, int c0) {
  for (int i = t; i < 1024; i += 256) {
    int b = i >> 5, cc = i & 31, d = c0 + cc;
    float gr = gi[i] + bih[d];
    float gz = gi[1024 + i] + bih[512 + d];
    float gn = gi[2048 + i] + bih[1024 + d];
    float hr = gh[b * 32 + cc] + bhh[d];
    float hz = gh[1024 + b * 32 + cc] + bhh[512 + d];
    float hn = gh[2048 + b * 32 + cc] + bhh[1024 + d];
    float r = sigm(gr + hr), z = sigm(gz + hz);
    float nn = tanhf(gn + r * hn);
    float hp = hF[b * 512 + d];
    float hnew = (1.f - z) * nn + z * hp;
    hF[b * 512 + d] = hnew;
    hb_out[b * 512 + d] = f2bf(hnew);
  }
}

// ---------------- persistent encoder scan (R5 acquire-poll + giP2 prefetch) ----------------
__global__ __launch_bounds__(256, 1) void k_enc_scan(
    const unsigned short* __restrict__ whhB, const float* __restrict__ giP2,
    const float* __restrict__ bih, const float* __restrict__ bhh,
    float* __restrict__ hF, unsigned short* __restrict__ hbA,
    unsigned short* __restrict__ hbB, int* __restrict__ arr) {
  __shared__ unsigned short hb[32 * 512];
  __shared__ float gh[3 * 1024];
  __shared__ float h32[1024];
  __shared__ float gi_lds[3072];
  int t = threadIdx.x, bid = blockIdx.x;
  int c0 = bid * 32;
  int lane = t & 63, g = t >> 6;
  int b31 = lane & 31, kg = lane >> 5;

  short8 wreg[32];
  if (g < 3) {
    const unsigned short* brow = whhB + (size_t)(g * 512 + c0 + b31) * 512 + kg * 8;
#pragma unroll
    for (int kk = 0; kk < 32; ++kk) wreg[kk] = *(const short8*)(brow + kk * 16);
  }
  for (int i = t; i < 1024; i += 256) h32[i] = 0.f;
  int cc = t & 31, d = c0 + cc;
  float bi_r = bih[d], bi_z = bih[512 + d], bi_n = bih[1024 + d];
  float bh_r = bhh[d], bh_z = bhh[512 + d], bh_n = bhh[1024 + d];
  int asw = (b31 & 15) << 4;
  {
    const float* src0 = giP2 + (size_t)bid * 3072;
#pragma unroll
    for (int i = 0; i < 3; ++i)
      gl_lds16(src0 + i * 1024 + t * 4, &gi_lds[i * 1024 + t * 4]);
  }
  __syncthreads();

  for (int s = 0; s < T_STEPS; ++s) {
    const unsigned short* hbin = (s & 1) ? hbB : hbA;
    unsigned short* hbout = (s & 1) ? hbA : hbB;
    if (s > 0 && t < 64) {
      for (;;) {
        int v = __hip_atomic_load(&arr[t & 15], __ATOMIC_ACQUIRE, __HIP_MEMORY_SCOPE_AGENT);
        if (__all(v >= s)) break;
        __builtin_amdgcn_s_sleep(1);
      }
    }
    __syncthreads();
    stage_hb(hbin, hb, t);
    __syncthreads();
    if (g < 3) {
      f32x16 acc0, acc1;
#pragma unroll
      for (int q = 0; q < 16; ++q) { acc0[q] = 0.f; acc1[q] = 0.f; }
      const char* abase = (const char*)hb + b31 * 1024;
#pragma unroll
      for (int kk = 0; kk < 32; ++kk) {
        int kb = (kk * 32 + kg * 16) ^ asw;
        short8 a = *(const short8*)(abase + kb);
        if (kk & 1) acc1 = __builtin_amdgcn_mfma_f32_32x32x16_bf16(a, wreg[kk], acc1, 0, 0, 0);
        else acc0 = __builtin_amdgcn_mfma_f32_32x32x16_bf16(a, wreg[kk], acc0, 0, 0, 0);
      }
#pragma unroll
      for (int q = 0; q < 16; ++q) {
        int br = (q & 3) + 8 * (q >> 2) + 4 * kg;
        gh[g * 1024 + br * 32 + b31] = acc0[q] + acc1[q];
      }
    }
    __syncthreads();
#pragma unroll
    for (int j = 0; j < 4; ++j) {
      int i = t + 256 * j;
      int b = (t >> 5) + 8 * j;
      float r = sigm(gi_lds[i] + bi_r + gh[i] + bh_r);
      float z = sigm(gi_lds[1024 + i] + bi_z + gh[1024 + i] + bh_z);
      float nn = tanhf(gi_lds[2048 + i] + bi_n + r * (gh[2048 + i] + bh_n));
      float hnew = (1.f - z) * nn + z * h32[i];
      h32[i] = hnew;
      hbout[b * 512 + d] = f2bf(hnew);
    }
    __syncthreads();
    if (g == 3 && s + 1 < T_STEPS) {
      const float* srcn = giP2 + (size_t)((s + 1) * 16 + bid) * 3072;
#pragma unroll
      for (int i = 0; i < 12; ++i)
        gl_lds16(srcn + (i * 64 + lane) * 4, &gi_lds[(i * 64 + lane) * 4]);
    }
    if (t == 0) {
      __threadfence();
      __hip_atomic_store(&arr[bid], s + 1, __ATOMIC_RELEASE, __HIP_MEMORY_SCOPE_AGENT);
    }
  }
#pragma unroll
  for (int j = 0; j < 4; ++j) {
    int i = t + 256 * j;
    int b = (t >> 5) + 8 * j;
    hF[b * 512 + d] = h32[i];
  }
}

// ---------------- persistent decoder: all 16 steps in one kernel ----------------
// 120 blocks. P1: gi GEMM (ntile=bid/10, kc=bid%10). P2: GRU (bid<16). P3: fc+agg (bid<32).
// Sense barrier: release flags[bid]=ph; wave0 polls all (relaxed) + fence.
__global__ __launch_bounds__(256, 2) void k_dec_all(
    const unsigned short* __restrict__ wihD, const unsigned short* __restrict__ whhB,
    const float* __restrict__ Wd, const float* __restrict__ bd,
    const float* __restrict__ bih, const float* __restrict__ bhh,
    const float* __restrict__ fcW, const float* __restrict__ fcb,
    const int* __restrict__ rowptr, const int* __restrict__ colA, const float* __restrict__ nrmA,
    const float* __restrict__ dec0, float* __restrict__ hF,
    unsigned short* __restrict__ hbX, unsigned short* __restrict__ hbY,
    float* __restrict__ parts, float* __restrict__ sbuf, float* __restrict__ out,
    int* __restrict__ flags) {
  __shared__ char smem[57344];
  int bid = blockIdx.x, t = threadIdx.x;
  int ph = 0;

#define DBAR()                                                                                 \
  do {                                                                                         \
    __syncthreads();                                                                           \
    ++ph;                                                                                      \
    if (t == 0) {                                                                              \
      __threadfence();                                                                         \
      __hip_atomic_store(&flags[bid], ph, __ATOMIC_RELEASE, __HIP_MEMORY_SCOPE_AGENT);         \
    }                                                                                          \
    if (t < 64) {                                                                              \
      for (;;) {                                                                               \
        bool ok = true;                                                                        \
        _Pragma("unroll")                                                                      \
        for (int i_ = 0; i_ < 2; ++i_) {                                                       \
          int idx_ = t + 64 * i_;                                                              \
          if (idx_ < DBLK)                                                                     \
            ok &= (__hip_atomic_load(&flags[idx_], __ATOMIC_RELAXED,                           \
                                     __HIP_MEMORY_SCOPE_AGENT) >= ph);                         \
        }                                                                                      \
        if (__all(ok)) break;                                                                  \
        __builtin_amdgcn_s_sleep(2);                                                           \
      }                                                                                        \
      __threadfence();                                                                         \
    }                                                                                          \
    __syncthreads();                                                                           \
  } while (0)

  // ---- P0: sbuf from decoder_initial_input (blocks 0..31)
  if (bid < NB) {
    float* irow = (float*)smem;
    for (int n = t; n < N_NODES; n += 256) irow[n] = dec0[bid * N_NODES + n];
    __syncthreads();
    for (int n = t; n < N_NODES; n += 256) {
      int e1 = rowptr[n + 1];
      float a = 0.f;
      for (int e = rowptr[n]; e < e1; ++e) a += nrmA[e] * irow[colA[e]];
      sbuf[bid * N_NODES + n] = a;
    }
  }
  DBAR();

  for (int s = 0; s < DSTEPS; ++s) {
    // ---- P1: parts[kc] = E8(on-the-fly) . Wih^T  (all 120 blocks)
    {
      float* s_lds = (float*)smem;  // [32][51]
      int ntile = bid / DKC, kc = bid - ntile * DKC;
      for (int i = t; i < 1600; i += 256) {
        int b = i / 50, nn = i - b * 50;
        s_lds[b * 51 + nn] = sbuf[b * N_NODES + kc * 50 + nn];
      }
      int lane = t & 63, w = t >> 6;
      int b31 = lane & 31, kg = lane >> 5;
      float wd8[8], bd8[8];
#pragma unroll
      for (int j = 0; j < 8; ++j) { wd8[j] = Wd[kg * 8 + j]; bd8[j] = bd[kg * 8 + j]; }
      __syncthreads();
      f32x16 acc;
#pragma unroll
      for (int q = 0; q < 16; ++q) acc[q] = 0.f;
      const unsigned short* brow =
          wihD + (size_t)(ntile * 128 + w * 32 + b31) * NH + kc * 800 + kg * 8;
      for (int kk = 0; kk < 50; ++kk) {
        float sv = s_lds[b31 * 51 + kk];
        short8 av;
#pragma unroll
        for (int j = 0; j < 8; ++j) av[j] = (short)f2bf(fmaxf(sv * wd8[j] + bd8[j], 0.f));
        short8 bv = *(const short8*)(brow + kk * 16);
        acc = __builtin_amdgcn_mfma_f32_32x32x16_bf16(av, bv, acc, 0, 0, 0);
      }
      int colo = ntile * 128 + w * 32 + b31;
#pragma unroll
      for (int q = 0; q < 16; ++q) {
        int br = (q & 3) + 8 * (q >> 2) + 4 * kg;
        parts[(size_t)kc * (NB * G3) + br * G3 + colo] = acc[q];
      }
    }
    DBAR();
    // ---- P2: GRU step (blocks 0..15)
    if (bid < 16) {
      unsigned short* hb = (unsigned short*)smem;
      float* gh = (float*)(smem + 32768);
      float* gi = (float*)(smem + 45056);
      const unsigned short* hbin = (s & 1) ? hbY : hbX;
      unsigned short* hbout = (s & 1) ? hbX : hbY;
      int c0 = bid * 32;
      stage_hb(hbin, hb, t);
      for (int i = t; i < 3072; i += 256) {
        int gg = i >> 10, r = i & 1023, bb = r >> 5, cc2 = r & 31;
        int dd = gg * 512 + c0 + cc2;
        float a = 0.f;
#pragma unroll
        for (int kc = 0; kc < DKC; ++kc) a += parts[(size_t)kc * (NB * G3) + bb * G3 + dd];
        gi[i] = a;
      }
      __syncthreads();
      gru_core_g(whhB, hb, gh, t, c0);
      __syncthreads();
      gru_gates(gi, gh, bih, bhh, hF, hbout, t, c0);
    }
    DBAR();
    // ---- P3: fc + out + next-step aggregation (blocks 0..31)
    if (bid < NB) {
      float* hrow = (float*)smem;
      float* orow = (float*)(smem + 2048);
      int b = bid;
      hrow[t] = hF[b * 512 + t];
      hrow[t + 256] = hF[b * 512 + t + 256];
      __syncthreads();
      for (int n = t; n < N_NODES; n += 256) {
        const float4* wr = (const float4*)(fcW + (size_t)n * DH);
        float a = 0.f;
#pragma unroll 4
        for (int k = 0; k < 128; ++k) {
          float4 wv = wr[k];
          const float4 hv = *(const float4*)&hrow[k * 4];
          a += wv.x * hv.x + wv.y * hv.y + wv.z * hv.z + wv.w * hv.w;
        }
        float o = a + fcb[n];
        orow[n] = o;
        out[(size_t)b * (DSTEPS * N_NODES) + s * N_NODES + n] = o;
      }
      __syncthreads();
      for (int n = t; n < N_NODES; n += 256) {
        int e1 = rowptr[n + 1];
        float a = 0.f;
        for (int e = rowptr[n]; e < e1; ++e) a += nrmA[e] * orow[colA[e]];
        sbuf[b * N_NODES + n] = a;
      }
    }
    DBAR();
  }
#undef DBAR
}

extern "C" void kernel_launch(void* const* d_in, const int* in_sizes, int n_in,
                              void* d_out, int out_size, void* d_ws, size_t ws_size,
                              hipStream_t stream) {
  const float* x = (const float*)d_in[0];
  const float* dec0 = (const float*)d_in[1];
  const int* ei = (const int*)d_in[2];
  const float* gWe = (const float*)d_in[3];
  const float* gbe = (const float*)d_in[4];
  const float* gWd = (const float*)d_in[5];
  const float* gbd = (const float*)d_in[6];
  const float* eWih = (const float*)d_in[7];
  const float* eWhh = (const float*)d_in[8];
  const float* ebih = (const float*)d_in[9];
  const float* ebhh = (const float*)d_in[10];
  const float* dWih = (const float*)d_in[11];
  const float* dWhh = (const float*)d_in[12];
  const float* dbih = (const float*)d_in[13];
  const float* dbhh = (const float*)d_in[14];
  const float* fcW = (const float*)d_in[15];
  const float* fcb = (const float*)d_in[16];
  float* out = (float*)d_out;
  (void)in_sizes; (void)n_in; (void)out_size; (void)ws_size;

  char* w = (char*)d_ws;
  size_t off = 0;
  auto alloc = [&](size_t bytes) -> void* {
    void* p = w + off;
    off = (off + bytes + 255) & ~(size_t)255;
    return p;
  };
  int* deg = (int*)alloc(512 * 4);
  float* dinv = (float*)alloc(512 * 4);
  int* rowptr = (int*)alloc(512 * 4);
  int* cursor = (int*)alloc(512 * 4);
  int* colA = (int*)alloc(E_TOT * 4);
  float* nrmA = (float*)alloc(E_TOT * 4);
  unsigned short* whhE = (unsigned short*)alloc((size_t)G3 * DH * 2);
  unsigned short* whhD = (unsigned short*)alloc((size_t)G3 * DH * 2);
  unsigned short* AhatD = (unsigned short*)alloc(512 * 512 * 2);
  float* hF = (float*)alloc(NB * DH * 4);                     // | contiguous:
  unsigned short* hbX = (unsigned short*)alloc(NB * DH * 2);  // | one memset
  int* arr = (int*)alloc(256);                                // |
  int* dflags = (int*)alloc(1024);                            // |
  unsigned short* hbY = (unsigned short*)alloc(NB * DH * 2);
  float* sbuf = (float*)alloc((size_t)NB * N_NODES * 4);
  unsigned short* emb = (unsigned short*)alloc((size_t)BT * NH * 2);
  char* wihE_parts = (char*)alloc((size_t)G3 * NH * 2);   // wihE, later parts
  unsigned short* wihE = (unsigned short*)wihE_parts;
  float* parts = (float*)wihE_parts;
  unsigned short* wihD = (unsigned short*)alloc((size_t)G3 * NH * 2);
  char* xT2_giP = (char*)alloc((size_t)16384 * 512 * 2);  // xT2, later giP2
  unsigned short* xT2 = (unsigned short*)xT2_giP;
  float* giP2 = (float*)xT2_giP;

  // zero hF + hbX + arr + dflags (contiguous)
  hipMemsetAsync(hF, 0, NB * DH * 4 + NB * DH * 2 + 256 + 1024, stream);

  k_deg_init<<<2, 256, 0, stream>>>(deg);
  k_deg_count<<<(E_EDGES + 255) / 256, 256, 0, stream>>>(ei, deg);
  k_scan<<<1, 512, 0, stream>>>(deg, dinv, rowptr, cursor);
  k_scatter<<<(E_TOT + 255) / 256, 256, 0, stream>>>(ei, dinv, cursor, colA, nrmA);

  int n4w = G3 * NH / 4;
  int n4h = G3 * DH / 4;
  k_f2bf4<<<(n4w + 255) / 256, 256, 0, stream>>>(eWih, wihE, n4w);
  k_f2bf4<<<(n4w + 255) / 256, 256, 0, stream>>>(dWih, wihD, n4w);
  k_f2bf4<<<(n4h + 255) / 256, 256, 0, stream>>>(eWhh, whhE, n4h);
  k_f2bf4<<<(n4h + 255) / 256, 256, 0, stream>>>(dWhh, whhD, n4h);

  k_transpose<<<BT, 256, 0, stream>>>(x, xT2);
  k_densify<<<512, 256, 0, stream>>>(rowptr, colA, nrmA, AhatD);
  k_gemm_agg<<<dim3(128, 4), 256, 0, stream>>>(xT2, AhatD, gWe, gbe, emb);

  k_gemm_enc<<<dim3(BT / 128, G3 / 64), 256, 0, stream>>>(emb, wihE, giP2);

  k_enc_scan<<<16, 256, 0, stream>>>(whhE, giP2, ebih, ebhh, hF, hbX, hbY, arr);

  k_dec_all<<<DBLK, 256, 0, stream>>>(wihD, whhD, gWd, gbd, dbih, dbhh, fcW, fcb,
                                      rowptr, colA, nrmA, dec0, hF, hbX, hbY,
                                      parts, sbuf, out, dflags);
}